// Round 8
// baseline (1247.467 us; speedup 1.0000x reference)
//
#include <hip/hip_runtime.h>

#define NPTS 4096
#define NSAMP 1024
#define KNN_K 32
#define FDIM 64
#define EPSF 1e-5f

typedef float v2f __attribute__((ext_vector_type(2)));

// ---------------------------------------------------------------------------
// K1: farthest point sampling. One block per batch, 512 threads (8 waves,
// 2 waves/SIMD -> sibling wave hides serial latency). 8 points/lane (4 pk
// pairs). Per-step: pk-f32 dist update (contract off, bit-exact vs numpy),
// fmax tree + reverse equality scan (selects winner idx AND xyz, first-index
// tie-break), then DPP argmax over the packed 44-bit key
// (dist_bits<<12)|(4095-idx) CARRYING the winner xyz as payload. Wave winners
// -> 20B LDS slots; ONE barrier; 3-step DPP over 8 slots; readlane gives both
// `far` and the next centroid in SGPRs (no pts[] array, no LDS re-fetch).
// ---------------------------------------------------------------------------
#define DPP_STEP(CTRL)                                                           \
  do {                                                                           \
    unsigned _olo = (unsigned)__builtin_amdgcn_update_dpp(0, (int)klo, CTRL,     \
                                                          0xf, 0xf, true);       \
    unsigned _ohi = (unsigned)__builtin_amdgcn_update_dpp(0, (int)khi, CTRL,     \
                                                          0xf, 0xf, true);       \
    unsigned _ox = (unsigned)__builtin_amdgcn_update_dpp(0, (int)wx, CTRL, 0xf,  \
                                                         0xf, true);             \
    unsigned _oy = (unsigned)__builtin_amdgcn_update_dpp(0, (int)wy, CTRL, 0xf,  \
                                                         0xf, true);             \
    unsigned _oz = (unsigned)__builtin_amdgcn_update_dpp(0, (int)wz, CTRL, 0xf,  \
                                                         0xf, true);             \
    unsigned long long _ok = ((unsigned long long)_ohi << 32) | _olo;            \
    unsigned long long _ck = ((unsigned long long)khi << 32) | klo;              \
    if (_ok > _ck) { klo = _olo; khi = _ohi; wx = _ox; wy = _oy; wz = _oz; }     \
  } while (0)

__global__ __launch_bounds__(512) void fps_kernel(const float* __restrict__ xyz,
                                                  int* __restrict__ fps_idx,
                                                  float* __restrict__ sqnorm) {
#pragma clang fp contract(off)
  __shared__ uint4 slotA[2][8];
  __shared__ unsigned slotZ[2][8];
  __shared__ int fpsb[NSAMP];
  const int b = blockIdx.x, t = threadIdx.x;
  const int lane = t & 63, w = t >> 6;
  const float* xb = xyz + (size_t)b * 3 * NPTS;
  v2f px[4], py[4], pz[4];
  float dist[8];
#pragma unroll
  for (int j = 0; j < 4; ++j) {
    int p0 = (2 * j) * 512 + t, p1 = (2 * j + 1) * 512 + t;
    float x0 = xb[p0], y0 = xb[NPTS + p0], z0 = xb[2 * NPTS + p0];
    float x1 = xb[p1], y1 = xb[NPTS + p1], z1 = xb[2 * NPTS + p1];
    float sq0 = __fadd_rn(__fadd_rn(__fmul_rn(x0, x0), __fmul_rn(y0, y0)),
                          __fmul_rn(z0, z0));
    float sq1 = __fadd_rn(__fadd_rn(__fmul_rn(x1, x1), __fmul_rn(y1, y1)),
                          __fmul_rn(z1, z1));
    sqnorm[b * NPTS + p0] = sq0;
    sqnorm[b * NPTS + p1] = sq1;
    px[j].x = x0; px[j].y = x1;
    py[j].x = y0; py[j].y = y1;
    pz[j].x = z0; pz[j].y = z1;
    dist[2 * j] = 1e10f;
    dist[2 * j + 1] = 1e10f;
  }
  if (t == 0) fpsb[0] = 0;
  // initial centroid = point 0 (uniform one-time global load)
  float cx = xb[0], cy = xb[NPTS], cz = xb[2 * NPTS];
  for (int it = 1; it < NSAMP; ++it) {
    v2f vcx, vcy, vcz;
    vcx.x = cx; vcx.y = cx;
    vcy.x = cy; vcy.y = cy;
    vcz.x = cz; vcz.y = cz;
#pragma unroll
    for (int j = 0; j < 4; ++j) {
      v2f dx = px[j] - vcx;
      v2f dy = py[j] - vcy;
      v2f dz = pz[j] - vcz;
      v2f dd = (dx * dx + dy * dy) + dz * dz;
      dist[2 * j] = fminf(dist[2 * j], dd.x);
      dist[2 * j + 1] = fminf(dist[2 * j + 1], dd.y);
    }
    // per-lane max (exact value-max)
    float m0 = fmaxf(dist[0], dist[1]), m1 = fmaxf(dist[2], dist[3]);
    float m2 = fmaxf(dist[4], dist[5]), m3 = fmaxf(dist[6], dist[7]);
    float mv = fmaxf(fmaxf(m0, m1), fmaxf(m2, m3));
    // reverse equality scan: lowest slot k attaining mv, selecting idx AND xyz
    unsigned ri = 7u;
    float sx = px[3].y, sy = py[3].y, sz = pz[3].y;
#pragma unroll
    for (int k = 6; k >= 0; --k) {
      bool e = (dist[k] == mv);
      ri = e ? (unsigned)k : ri;
      sx = e ? ((k & 1) ? px[k >> 1].y : px[k >> 1].x) : sx;
      sy = e ? ((k & 1) ? py[k >> 1].y : py[k >> 1].x) : sy;
      sz = e ? ((k & 1) ? pz[k >> 1].y : pz[k >> 1].x) : sz;
    }
    unsigned idx = (ri << 9) + (unsigned)t;  // k*512 + t
    unsigned mvb = __float_as_uint(mv);
    unsigned klo = (mvb << 12) | (4095u - idx);
    unsigned khi = mvb >> 20;
    unsigned wx = __float_as_uint(sx), wy = __float_as_uint(sy),
             wz = __float_as_uint(sz);
    // intra-wave argmax with xyz payload -> lane 63
    DPP_STEP(0x111);
    DPP_STEP(0x112);
    DPP_STEP(0x114);
    DPP_STEP(0x118);
    DPP_STEP(0x142);
    DPP_STEP(0x143);
    const int buf = it & 1;
    if (lane == 63) {
      slotA[buf][w] = make_uint4(klo, khi, wx, wy);
      slotZ[buf][w] = wz;
    }
    __syncthreads();
    // all waves reduce the 8 wave-winner slots redundantly (no 2nd barrier)
    uint4 q = slotA[buf][lane & 7];
    unsigned zz = slotZ[buf][lane & 7];
    klo = q.x; khi = q.y; wx = q.z; wy = q.w; wz = zz;
    DPP_STEP(0x111);
    DPP_STEP(0x112);
    DPP_STEP(0x114);
    unsigned flo = (unsigned)__builtin_amdgcn_readlane((int)klo, 7);
    int far = 4095 - (int)(flo & 0xfffu);
    cx = __uint_as_float((unsigned)__builtin_amdgcn_readlane((int)wx, 7));
    cy = __uint_as_float((unsigned)__builtin_amdgcn_readlane((int)wy, 7));
    cz = __uint_as_float((unsigned)__builtin_amdgcn_readlane((int)wz, 7));
    if (t == 0) fpsb[it] = far;
  }
  __syncthreads();
#pragma unroll
  for (int k = 0; k < 2; ++k)
    fps_idx[b * NSAMP + k * 512 + t] = fpsb[k * 512 + t];
}

// ---------------------------------------------------------------------------
// K2a: gather centroid features -> out1 (B,64,S) and ws new_feats (B,S,64)
// ---------------------------------------------------------------------------
__global__ __launch_bounds__(256) void gather_feats_kernel(const float* __restrict__ feats,
                                                           const int* __restrict__ fps,
                                                           float* __restrict__ out1,
                                                           float* __restrict__ nf) {
  int i = blockIdx.x * 256 + threadIdx.x;  // 8*64*1024
  int s = i & 1023, c = (i >> 10) & 63, b = i >> 16;
  int p = fps[(b << 10) + s];
  float v = feats[((size_t)(b * 64 + c)) * NPTS + p];
  out1[(b * 64 + c) * 1024 + s] = v;
  nf[(((b << 10) + s) << 6) + c] = v;
}

// ---------------------------------------------------------------------------
// K2b: gather centroid coords -> out0 (B,3,S) and ws float4 (x,y,z,|.|^2)
// ---------------------------------------------------------------------------
__global__ __launch_bounds__(256) void gather_xyz_kernel(const float* __restrict__ xyz,
                                                         const float* __restrict__ sqnorm,
                                                         const int* __restrict__ fps,
                                                         float* __restrict__ out0,
                                                         float4* __restrict__ nx4) {
  int i = blockIdx.x * 256 + threadIdx.x;  // 8192
  int b = i >> 10, s = i & 1023;
  int p = fps[i];
  const float* xb = xyz + (size_t)b * 3 * NPTS;
  float x = xb[p], y = xb[NPTS + p], z = xb[2 * NPTS + p];
  nx4[i] = make_float4(x, y, z, sqnorm[b * NPTS + p]);
  out0[(b * 3 + 0) * 1024 + s] = x;
  out0[(b * 3 + 1) * 1024 + s] = y;
  out0[(b * 3 + 2) * 1024 + s] = z;
}

// ---------------------------------------------------------------------------
// K3: exact ordered top-32 nearest neighbors per (b,s).
// One wave per row; 64 distance keys per lane in VGPRs, key = (mapped_bits<<32)|n
// so ascending-u64 order == ascending (distance, index) order (lax.top_k ties).
// dot uses an FMA-accumulated chain (matches the reference einsum lowering).
// ---------------------------------------------------------------------------
__device__ __forceinline__ unsigned long long mk_key(float xn, float yn, float zn,
                                                     float sq, float cx, float cy,
                                                     float cz, float src2, int n) {
  float dot = __fmaf_rn(zn, cz, __fmaf_rn(yn, cy, __fmul_rn(xn, cx)));
  float d = __fadd_rn(__fadd_rn(__fmul_rn(-2.0f, dot), src2), sq);
  unsigned mb = __float_as_uint(d);
  mb = (mb & 0x80000000u) ? ~mb : (mb | 0x80000000u);
  return ((unsigned long long)mb << 32) | (unsigned)n;
}

__global__ __launch_bounds__(256, 2) void knn_kernel(const float* __restrict__ xyz,
                                                     const float* __restrict__ sqnorm,
                                                     const float4* __restrict__ nx4,
                                                     int* __restrict__ knn) {
  const int lane = threadIdx.x & 63;
  const int w = threadIdx.x >> 6;
  const int row = blockIdx.x * 4 + w;  // 0..8191
  const int b = row >> 10;
  const float4 c4 = nx4[row];
  const float cx = c4.x, cy = c4.y, cz = c4.z, src2 = c4.w;
  const float4* x4 = (const float4*)(xyz + (size_t)b * 3 * NPTS);
  const float4* y4 = (const float4*)(xyz + (size_t)b * 3 * NPTS + NPTS);
  const float4* z4 = (const float4*)(xyz + (size_t)b * 3 * NPTS + 2 * NPTS);
  const float4* s4 = (const float4*)(sqnorm + (size_t)b * NPTS);
  unsigned long long key[64];
#pragma unroll
  for (int jj = 0; jj < 16; ++jj) {
    int vi = jj * 64 + lane;
    float4 xv = x4[vi], yv = y4[vi], zv = z4[vi], sv = s4[vi];
    int n0 = vi * 4;
    key[jj * 4 + 0] = mk_key(xv.x, yv.x, zv.x, sv.x, cx, cy, cz, src2, n0);
    key[jj * 4 + 1] = mk_key(xv.y, yv.y, zv.y, sv.y, cx, cy, cz, src2, n0 + 1);
    key[jj * 4 + 2] = mk_key(xv.z, yv.z, zv.z, sv.z, cx, cy, cz, src2, n0 + 2);
    key[jj * 4 + 3] = mk_key(xv.w, yv.w, zv.w, sv.w, cx, cy, cz, src2, n0 + 3);
  }
  unsigned long long last = 0ull;
  const int out_base = row * KNN_K;
#pragma unroll 1
  for (int r = 0; r < KNN_K; ++r) {
    unsigned long long cur = ~0ull;
#pragma unroll
    for (int j = 0; j < 64; ++j) {
      unsigned long long k = key[j];
      if (k > last && k < cur) cur = k;
    }
#pragma unroll
    for (int off = 32; off > 0; off >>= 1) {
      unsigned long long o = __shfl_xor(cur, off);
      cur = (o < cur) ? o : cur;
    }
    last = cur;
    if (lane == r) knn[out_base + r] = (int)(unsigned)(cur & 0xffffffffull);
  }
}

// ---------------------------------------------------------------------------
// K4: per-batch sum / sumsq of diff (f64) for std(ddof=1)
// ---------------------------------------------------------------------------
__global__ __launch_bounds__(256) void stats_kernel(const float* __restrict__ feats,
                                                    const float* __restrict__ nf,
                                                    const int* __restrict__ knn,
                                                    double* __restrict__ stats) {
  const int b = blockIdx.x >> 5;
  const int chunk = blockIdx.x & 31;
  const int base = chunk * 65536;
  double sm = 0.0, sq = 0.0;
  for (int i = 0; i < 256; ++i) {
    int e = base + i * 256 + threadIdx.x;   // e < 2097152 per batch
    int c = e >> 15;                        // 0..63
    int sk = e & 32767;
    int s = sk >> 5, j = sk & 31;
    int p = knn[((((b << 10) + s)) << 5) + j];
    float f = feats[((size_t)(b * 64 + c)) * NPTS + p];
    float m = nf[(((b << 10) + s) << 6) + c];
    double d = (double)__fsub_rn(f, m);
    sm += d;
    sq += d * d;
  }
#pragma unroll
  for (int off = 32; off > 0; off >>= 1) {
    sm += __shfl_down(sm, off);
    sq += __shfl_down(sq, off);
  }
  __shared__ double red[8];
  int w = threadIdx.x >> 6;
  if ((threadIdx.x & 63) == 0) { red[w * 2] = sm; red[w * 2 + 1] = sq; }
  __syncthreads();
  if (threadIdx.x == 0) {
    atomicAdd(&stats[b * 2 + 0], red[0] + red[2] + red[4] + red[6]);
    atomicAdd(&stats[b * 2 + 1], red[1] + red[3] + red[5] + red[7]);
  }
}

// ---------------------------------------------------------------------------
// K5: final normalized/affine output, (B,128,S,k) coalesced along (s,k)
// ---------------------------------------------------------------------------
__global__ __launch_bounds__(256) void out_kernel(const float* __restrict__ feats,
                                                  const float* __restrict__ nf,
                                                  const int* __restrict__ knn,
                                                  const double* __restrict__ stats,
                                                  const float* __restrict__ alpha,
                                                  const float* __restrict__ beta,
                                                  float* __restrict__ out2) {
  const int plane = blockIdx.x;  // b*64 + c
  const int b = plane >> 6, c = plane & 63;
  const int sk = blockIdx.y * 256 + threadIdx.x;  // 0..32767
  const int s = sk >> 5, j = sk & 31;
  const double n = 2097152.0;
  double sm = stats[b * 2], sqs = stats[b * 2 + 1];
  double var = (sqs - sm * sm / n) / (n - 1.0);
  float stdf = (float)sqrt(var);
  float denom = stdf + EPSF;
  int p = knn[((((b << 10) + s)) << 5) + j];
  float f = feats[((size_t)(b * 64 + c)) * NPTS + p];
  float m = nf[(((b << 10) + s) << 6) + c];
  float diff = __fsub_rn(f, m);
  float g = alpha[c] * (diff / denom) + beta[c];
  size_t o1 = (((size_t)(b * 128 + c) << 10) + (size_t)s) * 32 + j;
  size_t o2 = (((size_t)(b * 128 + 64 + c) << 10) + (size_t)s) * 32 + j;
  out2[o1] = g;
  out2[o2] = g - m;
}

extern "C" void kernel_launch(void* const* d_in, const int* in_sizes, int n_in,
                              void* d_out, int out_size, void* d_ws, size_t ws_size,
                              hipStream_t stream) {
  (void)in_sizes; (void)n_in; (void)out_size; (void)ws_size;
  const float* xyz   = (const float*)d_in[0];  // (8,3,4096)
  const float* feats = (const float*)d_in[1];  // (8,64,4096)
  const float* alpha = (const float*)d_in[2];  // (64)
  const float* beta  = (const float*)d_in[3];  // (64)
  float* out  = (float*)d_out;
  float* out0 = out;                  // (8,3,1024)    = 24576
  float* out1 = out + 24576;          // (8,64,1024)   = 524288
  float* out2 = out + 24576 + 524288; // (8,128,1024,32)

  char* ws = (char*)d_ws;
  int*    fps   = (int*)ws;                   // 32768 B
  float*  sqn   = (float*)(ws + 32768);       // 131072 B
  float4* nx4   = (float4*)(ws + 163840);     // 131072 B (16B aligned)
  float*  nf    = (float*)(ws + 294912);      // 2097152 B
  int*    knn   = (int*)(ws + 2392064);       // 1048576 B
  double* stats = (double*)(ws + 3440640);    // 128 B

  hipMemsetAsync(stats, 0, 128, stream);
  fps_kernel<<<8, 512, 0, stream>>>(xyz, fps, sqn);
  gather_feats_kernel<<<2048, 256, 0, stream>>>(feats, fps, out1, nf);
  gather_xyz_kernel<<<32, 256, 0, stream>>>(xyz, sqn, fps, out0, nx4);
  knn_kernel<<<2048, 256, 0, stream>>>(xyz, sqn, nx4, knn);
  stats_kernel<<<256, 256, 0, stream>>>(feats, nf, knn, stats);
  out_kernel<<<dim3(512, 128), 256, 0, stream>>>(feats, nf, knn, stats, alpha, beta, out2);
}

// Round 9
// 1170.943 us; speedup vs baseline: 1.0654x; 1.0654x over previous
//
#include <hip/hip_runtime.h>

#define NPTS 4096
#define NSAMP 1024
#define KNN_K 32
#define FDIM 64
#define EPSF 1e-5f

typedef float v2f __attribute__((ext_vector_type(2)));

// ---------------------------------------------------------------------------
// K1: farthest point sampling. One block per batch, 512 threads (8 waves,
// 2 waves/SIMD: sibling wave hides serial latency -- the only config that
// worked, R3). Per-step issue minimized with individually-validated pieces:
//   - pk-f32 dist update (4 float2 pairs, contract off; bit-exact, R6/R7)
//   - 7-op fmax tree + 6-step scalar-f32 DPP fmax -> readlane(63)
//   - 8x ballot + SALU scan tie-break (exact lowest-index, R6)
//   - packed 44-bit key (dist<<12)|(4095-idx) cross-wave via LDS,
//     3-step DPP_MAX64, readlane -> far (R2-R4)
//   - single ds_read_b128 pts[far] for next centroid; ONE barrier/step.
// ---------------------------------------------------------------------------
#define DPP_FMAX(CTRL)                                                           \
  {                                                                              \
    int _o = __builtin_amdgcn_update_dpp(0, __float_as_int(wv), CTRL, 0xf, 0xf,  \
                                         true);                                  \
    wv = fmaxf(wv, __int_as_float(_o));                                          \
  }

#define DPP_MAX64(CTRL)                                                          \
  {                                                                              \
    unsigned _olo = (unsigned)__builtin_amdgcn_update_dpp(0, (int)klo, CTRL,     \
                                                          0xf, 0xf, true);       \
    unsigned _ohi = (unsigned)__builtin_amdgcn_update_dpp(0, (int)khi, CTRL,     \
                                                          0xf, 0xf, true);       \
    unsigned long long _ok = ((unsigned long long)_ohi << 32) | _olo;            \
    unsigned long long _ck = ((unsigned long long)khi << 32) | klo;              \
    if (_ok > _ck) { klo = _olo; khi = _ohi; }                                   \
  }

__global__ __launch_bounds__(512) void fps_kernel(const float* __restrict__ xyz,
                                                  int* __restrict__ fps_idx,
                                                  float* __restrict__ sqnorm) {
#pragma clang fp contract(off)
  __shared__ float4 pts[NPTS];
  __shared__ unsigned long long skeys[2][8];
  __shared__ int fpsb[NSAMP];
  const int b = blockIdx.x, t = threadIdx.x;
  const int lane = t & 63, w = t >> 6;
  const float* xb = xyz + (size_t)b * 3 * NPTS;
  v2f px[4], py[4], pz[4];
  float dist[8];
#pragma unroll
  for (int j = 0; j < 4; ++j) {
    int p0 = (2 * j) * 512 + t, p1 = (2 * j + 1) * 512 + t;
    float x0 = xb[p0], y0 = xb[NPTS + p0], z0 = xb[2 * NPTS + p0];
    float x1 = xb[p1], y1 = xb[NPTS + p1], z1 = xb[2 * NPTS + p1];
    float sq0 = __fadd_rn(__fadd_rn(__fmul_rn(x0, x0), __fmul_rn(y0, y0)),
                          __fmul_rn(z0, z0));
    float sq1 = __fadd_rn(__fadd_rn(__fmul_rn(x1, x1), __fmul_rn(y1, y1)),
                          __fmul_rn(z1, z1));
    pts[p0] = make_float4(x0, y0, z0, sq0);
    pts[p1] = make_float4(x1, y1, z1, sq1);
    sqnorm[b * NPTS + p0] = sq0;
    sqnorm[b * NPTS + p1] = sq1;
    px[j].x = x0; px[j].y = x1;
    py[j].x = y0; py[j].y = y1;
    pz[j].x = z0; pz[j].y = z1;
    dist[2 * j] = 1e10f;
    dist[2 * j + 1] = 1e10f;
  }
  if (t == 0) fpsb[0] = 0;
  __syncthreads();
  float4 c = pts[0];
  for (int it = 1; it < NSAMP; ++it) {
    v2f vcx, vcy, vcz;
    vcx.x = c.x; vcx.y = c.x;
    vcy.x = c.y; vcy.y = c.y;
    vcz.x = c.z; vcz.y = c.z;
#pragma unroll
    for (int j = 0; j < 4; ++j) {
      v2f dx = px[j] - vcx;
      v2f dy = py[j] - vcy;
      v2f dz = pz[j] - vcz;
      v2f dd = (dx * dx + dy * dy) + dz * dz;
      dist[2 * j] = fminf(dist[2 * j], dd.x);
      dist[2 * j + 1] = fminf(dist[2 * j + 1], dd.y);
    }
    // per-lane value max (7-op tree, exact)
    float m0 = fmaxf(dist[0], dist[1]), m1 = fmaxf(dist[2], dist[3]);
    float m2 = fmaxf(dist[4], dist[5]), m3 = fmaxf(dist[6], dist[7]);
    float wv = fmaxf(fmaxf(m0, m1), fmaxf(m2, m3));
    // wave value-max via scalar DPP chain -> lane 63 (dists >= 0)
    DPP_FMAX(0x111)
    DPP_FMAX(0x112)
    DPP_FMAX(0x114)
    DPP_FMAX(0x118)
    DPP_FMAX(0x142)
    DPP_FMAX(0x143)
    unsigned wvb = (unsigned)__builtin_amdgcn_readlane(__float_as_int(wv), 63);
    float wvf = __uint_as_float(wvb);
    // exact tie-break: first slot k (ascending global idx), then first lane
    int kk = 0, found = 0;
    unsigned long long mm = 0ull;
#pragma unroll
    for (int k = 0; k < 8; ++k) {
      unsigned long long m = __ballot(dist[k] == wvf);
      if (!found && m != 0ull) { kk = k; mm = m; found = 1; }
    }
    int fl = __ffsll(mm) - 1;
    unsigned idx = (unsigned)(kk * 512 + (w << 6) + fl);  // lowest idx @ wvf
    // packed 44-bit key: (dist_bits << 12) | (4095 - idx)
    unsigned klo = (wvb << 12) | (4095u - idx);
    unsigned khi = wvb >> 20;
    const int buf = it & 1;
    if (lane == 63) skeys[buf][w] = ((unsigned long long)khi << 32) | klo;
    __syncthreads();
    // all waves reduce the 8 wave-winners redundantly (no 2nd barrier)
    unsigned long long kk2 = skeys[buf][lane & 7];
    klo = (unsigned)kk2;
    khi = (unsigned)(kk2 >> 32);
    DPP_MAX64(0x111)
    DPP_MAX64(0x112)
    DPP_MAX64(0x114)
    unsigned flo = (unsigned)__builtin_amdgcn_readlane((int)klo, 7);
    int far = 4095 - (int)(flo & 0xfffu);
    if (t == 0) fpsb[it] = far;
    c = pts[far];
  }
  __syncthreads();
#pragma unroll
  for (int k = 0; k < 2; ++k)
    fps_idx[b * NSAMP + k * 512 + t] = fpsb[k * 512 + t];
}

// ---------------------------------------------------------------------------
// K2a: gather centroid features -> out1 (B,64,S) and ws new_feats (B,S,64)
// ---------------------------------------------------------------------------
__global__ __launch_bounds__(256) void gather_feats_kernel(const float* __restrict__ feats,
                                                           const int* __restrict__ fps,
                                                           float* __restrict__ out1,
                                                           float* __restrict__ nf) {
  int i = blockIdx.x * 256 + threadIdx.x;  // 8*64*1024
  int s = i & 1023, c = (i >> 10) & 63, b = i >> 16;
  int p = fps[(b << 10) + s];
  float v = feats[((size_t)(b * 64 + c)) * NPTS + p];
  out1[(b * 64 + c) * 1024 + s] = v;
  nf[(((b << 10) + s) << 6) + c] = v;
}

// ---------------------------------------------------------------------------
// K2b: gather centroid coords -> out0 (B,3,S) and ws float4 (x,y,z,|.|^2)
// ---------------------------------------------------------------------------
__global__ __launch_bounds__(256) void gather_xyz_kernel(const float* __restrict__ xyz,
                                                         const float* __restrict__ sqnorm,
                                                         const int* __restrict__ fps,
                                                         float* __restrict__ out0,
                                                         float4* __restrict__ nx4) {
  int i = blockIdx.x * 256 + threadIdx.x;  // 8192
  int b = i >> 10, s = i & 1023;
  int p = fps[i];
  const float* xb = xyz + (size_t)b * 3 * NPTS;
  float x = xb[p], y = xb[NPTS + p], z = xb[2 * NPTS + p];
  nx4[i] = make_float4(x, y, z, sqnorm[b * NPTS + p]);
  out0[(b * 3 + 0) * 1024 + s] = x;
  out0[(b * 3 + 1) * 1024 + s] = y;
  out0[(b * 3 + 2) * 1024 + s] = z;
}

// ---------------------------------------------------------------------------
// K3: exact ordered top-32 nearest neighbors per (b,s).
// One wave per row; 64 distance keys per lane in VGPRs, key = (mapped_bits<<32)|n
// so ascending-u64 order == ascending (distance, index) order (lax.top_k ties).
// dot uses an FMA-accumulated chain (matches the reference einsum lowering).
// ---------------------------------------------------------------------------
__device__ __forceinline__ unsigned long long mk_key(float xn, float yn, float zn,
                                                     float sq, float cx, float cy,
                                                     float cz, float src2, int n) {
  float dot = __fmaf_rn(zn, cz, __fmaf_rn(yn, cy, __fmul_rn(xn, cx)));
  float d = __fadd_rn(__fadd_rn(__fmul_rn(-2.0f, dot), src2), sq);
  unsigned mb = __float_as_uint(d);
  mb = (mb & 0x80000000u) ? ~mb : (mb | 0x80000000u);
  return ((unsigned long long)mb << 32) | (unsigned)n;
}

__global__ __launch_bounds__(256, 2) void knn_kernel(const float* __restrict__ xyz,
                                                     const float* __restrict__ sqnorm,
                                                     const float4* __restrict__ nx4,
                                                     int* __restrict__ knn) {
  const int lane = threadIdx.x & 63;
  const int w = threadIdx.x >> 6;
  const int row = blockIdx.x * 4 + w;  // 0..8191
  const int b = row >> 10;
  const float4 c4 = nx4[row];
  const float cx = c4.x, cy = c4.y, cz = c4.z, src2 = c4.w;
  const float4* x4 = (const float4*)(xyz + (size_t)b * 3 * NPTS);
  const float4* y4 = (const float4*)(xyz + (size_t)b * 3 * NPTS + NPTS);
  const float4* z4 = (const float4*)(xyz + (size_t)b * 3 * NPTS + 2 * NPTS);
  const float4* s4 = (const float4*)(sqnorm + (size_t)b * NPTS);
  unsigned long long key[64];
#pragma unroll
  for (int jj = 0; jj < 16; ++jj) {
    int vi = jj * 64 + lane;
    float4 xv = x4[vi], yv = y4[vi], zv = z4[vi], sv = s4[vi];
    int n0 = vi * 4;
    key[jj * 4 + 0] = mk_key(xv.x, yv.x, zv.x, sv.x, cx, cy, cz, src2, n0);
    key[jj * 4 + 1] = mk_key(xv.y, yv.y, zv.y, sv.y, cx, cy, cz, src2, n0 + 1);
    key[jj * 4 + 2] = mk_key(xv.z, yv.z, zv.z, sv.z, cx, cy, cz, src2, n0 + 2);
    key[jj * 4 + 3] = mk_key(xv.w, yv.w, zv.w, sv.w, cx, cy, cz, src2, n0 + 3);
  }
  unsigned long long last = 0ull;
  const int out_base = row * KNN_K;
#pragma unroll 1
  for (int r = 0; r < KNN_K; ++r) {
    unsigned long long cur = ~0ull;
#pragma unroll
    for (int j = 0; j < 64; ++j) {
      unsigned long long k = key[j];
      if (k > last && k < cur) cur = k;
    }
#pragma unroll
    for (int off = 32; off > 0; off >>= 1) {
      unsigned long long o = __shfl_xor(cur, off);
      cur = (o < cur) ? o : cur;
    }
    last = cur;
    if (lane == r) knn[out_base + r] = (int)(unsigned)(cur & 0xffffffffull);
  }
}

// ---------------------------------------------------------------------------
// K4: per-batch sum / sumsq of diff (f64) for std(ddof=1)
// ---------------------------------------------------------------------------
__global__ __launch_bounds__(256) void stats_kernel(const float* __restrict__ feats,
                                                    const float* __restrict__ nf,
                                                    const int* __restrict__ knn,
                                                    double* __restrict__ stats) {
  const int b = blockIdx.x >> 5;
  const int chunk = blockIdx.x & 31;
  const int base = chunk * 65536;
  double sm = 0.0, sq = 0.0;
  for (int i = 0; i < 256; ++i) {
    int e = base + i * 256 + threadIdx.x;   // e < 2097152 per batch
    int c = e >> 15;                        // 0..63
    int sk = e & 32767;
    int s = sk >> 5, j = sk & 31;
    int p = knn[((((b << 10) + s)) << 5) + j];
    float f = feats[((size_t)(b * 64 + c)) * NPTS + p];
    float m = nf[(((b << 10) + s) << 6) + c];
    double d = (double)__fsub_rn(f, m);
    sm += d;
    sq += d * d;
  }
#pragma unroll
  for (int off = 32; off > 0; off >>= 1) {
    sm += __shfl_down(sm, off);
    sq += __shfl_down(sq, off);
  }
  __shared__ double red[8];
  int w = threadIdx.x >> 6;
  if ((threadIdx.x & 63) == 0) { red[w * 2] = sm; red[w * 2 + 1] = sq; }
  __syncthreads();
  if (threadIdx.x == 0) {
    atomicAdd(&stats[b * 2 + 0], red[0] + red[2] + red[4] + red[6]);
    atomicAdd(&stats[b * 2 + 1], red[1] + red[3] + red[5] + red[7]);
  }
}

// ---------------------------------------------------------------------------
// K5: final normalized/affine output, (B,128,S,k) coalesced along (s,k)
// ---------------------------------------------------------------------------
__global__ __launch_bounds__(256) void out_kernel(const float* __restrict__ feats,
                                                  const float* __restrict__ nf,
                                                  const int* __restrict__ knn,
                                                  const double* __restrict__ stats,
                                                  const float* __restrict__ alpha,
                                                  const float* __restrict__ beta,
                                                  float* __restrict__ out2) {
  const int plane = blockIdx.x;  // b*64 + c
  const int b = plane >> 6, c = plane & 63;
  const int sk = blockIdx.y * 256 + threadIdx.x;  // 0..32767
  const int s = sk >> 5, j = sk & 31;
  const double n = 2097152.0;
  double sm = stats[b * 2], sqs = stats[b * 2 + 1];
  double var = (sqs - sm * sm / n) / (n - 1.0);
  float stdf = (float)sqrt(var);
  float denom = stdf + EPSF;
  int p = knn[((((b << 10) + s)) << 5) + j];
  float f = feats[((size_t)(b * 64 + c)) * NPTS + p];
  float m = nf[(((b << 10) + s) << 6) + c];
  float diff = __fsub_rn(f, m);
  float g = alpha[c] * (diff / denom) + beta[c];
  size_t o1 = (((size_t)(b * 128 + c) << 10) + (size_t)s) * 32 + j;
  size_t o2 = (((size_t)(b * 128 + 64 + c) << 10) + (size_t)s) * 32 + j;
  out2[o1] = g;
  out2[o2] = g - m;
}

extern "C" void kernel_launch(void* const* d_in, const int* in_sizes, int n_in,
                              void* d_out, int out_size, void* d_ws, size_t ws_size,
                              hipStream_t stream) {
  (void)in_sizes; (void)n_in; (void)out_size; (void)ws_size;
  const float* xyz   = (const float*)d_in[0];  // (8,3,4096)
  const float* feats = (const float*)d_in[1];  // (8,64,4096)
  const float* alpha = (const float*)d_in[2];  // (64)
  const float* beta  = (const float*)d_in[3];  // (64)
  float* out  = (float*)d_out;
  float* out0 = out;                  // (8,3,1024)    = 24576
  float* out1 = out + 24576;          // (8,64,1024)   = 524288
  float* out2 = out + 24576 + 524288; // (8,128,1024,32)

  char* ws = (char*)d_ws;
  int*    fps   = (int*)ws;                   // 32768 B
  float*  sqn   = (float*)(ws + 32768);       // 131072 B
  float4* nx4   = (float4*)(ws + 163840);     // 131072 B (16B aligned)
  float*  nf    = (float*)(ws + 294912);      // 2097152 B
  int*    knn   = (int*)(ws + 2392064);       // 1048576 B
  double* stats = (double*)(ws + 3440640);    // 128 B

  hipMemsetAsync(stats, 0, 128, stream);
  fps_kernel<<<8, 512, 0, stream>>>(xyz, fps, sqn);
  gather_feats_kernel<<<2048, 256, 0, stream>>>(feats, fps, out1, nf);
  gather_xyz_kernel<<<32, 256, 0, stream>>>(xyz, sqn, fps, out0, nx4);
  knn_kernel<<<2048, 256, 0, stream>>>(xyz, sqn, nx4, knn);
  stats_kernel<<<256, 256, 0, stream>>>(feats, nf, knn, stats);
  out_kernel<<<dim3(512, 128), 256, 0, stream>>>(feats, nf, knn, stats, alpha, beta, out2);
}

// Round 10
// 977.030 us; speedup vs baseline: 1.2768x; 1.1985x over previous
//
#include <hip/hip_runtime.h>

#define NPTS 4096
#define NSAMP 1024
#define KNN_K 32
#define FDIM 64
#define EPSF 1e-5f

typedef float v2f __attribute__((ext_vector_type(2)));

// ---------------------------------------------------------------------------
// K1: farthest point sampling -- restored R3 structure (empirical best, 641us):
// one block per batch, 512 threads (8 waves, 2 waves/SIMD so sibling waves
// hide serial latency). 8 pts/lane. Per step: dist update (pk-f32 pairs,
// contract off -- bit-exact, validated R6/R7), serial ascending cmp/select
// per-lane argmax (first-index tie-break), packed 44-bit key
// (dist_bits<<12)|(4095-idx), 6x DPP_MAX64 -> lane 63 -> LDS slot, ONE
// barrier, redundant 3x DPP_MAX64 stage-2 on all waves, readlane -> far,
// pts[far] LDS broadcast read. t0 stores fps_idx (global) + fpsb (LDS).
// Epilogue: fused gather_xyz -- emits out0 (B,3,S) and nx4 from LDS pts.
// ---------------------------------------------------------------------------
#define DPP_MAX64(CTRL)                                                          \
  {                                                                              \
    unsigned _olo = (unsigned)__builtin_amdgcn_update_dpp(0, (int)klo, CTRL,     \
                                                          0xf, 0xf, true);       \
    unsigned _ohi = (unsigned)__builtin_amdgcn_update_dpp(0, (int)khi, CTRL,     \
                                                          0xf, 0xf, true);       \
    unsigned long long _ok = ((unsigned long long)_ohi << 32) | _olo;            \
    unsigned long long _ck = ((unsigned long long)khi << 32) | klo;              \
    if (_ok > _ck) { klo = _olo; khi = _ohi; }                                   \
  }

__global__ __launch_bounds__(512) void fps_kernel(const float* __restrict__ xyz,
                                                  int* __restrict__ fps_idx,
                                                  float* __restrict__ sqnorm,
                                                  float* __restrict__ out0,
                                                  float4* __restrict__ nx4) {
#pragma clang fp contract(off)
  __shared__ float4 pts[NPTS];
  __shared__ unsigned long long skeys[2][8];
  __shared__ int fpsb[NSAMP];
  const int b = blockIdx.x, t = threadIdx.x;
  const int lane = t & 63, w = t >> 6;
  const float* xb = xyz + (size_t)b * 3 * NPTS;
  v2f px[4], py[4], pz[4], dst[4];
#pragma unroll
  for (int j = 0; j < 4; ++j) {
    int p0 = (2 * j) * 512 + t, p1 = (2 * j + 1) * 512 + t;
    float x0 = xb[p0], y0 = xb[NPTS + p0], z0 = xb[2 * NPTS + p0];
    float x1 = xb[p1], y1 = xb[NPTS + p1], z1 = xb[2 * NPTS + p1];
    float sq0 = __fadd_rn(__fadd_rn(__fmul_rn(x0, x0), __fmul_rn(y0, y0)),
                          __fmul_rn(z0, z0));
    float sq1 = __fadd_rn(__fadd_rn(__fmul_rn(x1, x1), __fmul_rn(y1, y1)),
                          __fmul_rn(z1, z1));
    pts[p0] = make_float4(x0, y0, z0, sq0);
    pts[p1] = make_float4(x1, y1, z1, sq1);
    sqnorm[b * NPTS + p0] = sq0;
    sqnorm[b * NPTS + p1] = sq1;
    px[j].x = x0; px[j].y = x1;
    py[j].x = y0; py[j].y = y1;
    pz[j].x = z0; pz[j].y = z1;
    dst[j].x = 1e10f;
    dst[j].y = 1e10f;
  }
  if (t == 0) { fps_idx[b * NSAMP] = 0; fpsb[0] = 0; }
  __syncthreads();
  float4 c = pts[0];
  for (int it = 1; it < NSAMP; ++it) {
    v2f vcx, vcy, vcz;
    vcx.x = c.x; vcx.y = c.x;
    vcy.x = c.y; vcy.y = c.y;
    vcz.x = c.z; vcz.y = c.z;
#pragma unroll
    for (int j = 0; j < 4; ++j) {
      v2f dx = px[j] - vcx;
      v2f dy = py[j] - vcy;
      v2f dz = pz[j] - vcz;
      v2f dd = (dx * dx + dy * dy) + dz * dz;
      dst[j].x = fminf(dst[j].x, dd.x);
      dst[j].y = fminf(dst[j].y, dd.y);
    }
    // R3-style serial ascending argmax (first-index tie-break, interleavable)
    float bv = -1.0f;
    int bi = 0;
#pragma unroll
    for (int k = 0; k < 8; ++k) {
      float nd = (k & 1) ? dst[k >> 1].y : dst[k >> 1].x;
      int n = k * 512 + t;
      if (nd > bv) { bv = nd; bi = n; }  // k ascending -> lowest idx on tie
    }
    // packed 44-bit key: (dist_bits << 12) | (4095 - idx)
    unsigned bvb = __float_as_uint(bv);
    unsigned klo = (bvb << 12) | (unsigned)(4095 - bi);
    unsigned khi = bvb >> 20;
    // intra-wave argmax -> lane 63
    DPP_MAX64(0x111)
    DPP_MAX64(0x112)
    DPP_MAX64(0x114)
    DPP_MAX64(0x118)
    DPP_MAX64(0x142)
    DPP_MAX64(0x143)
    const int buf = it & 1;
    if (lane == 63) skeys[buf][w] = ((unsigned long long)khi << 32) | klo;
    __syncthreads();
    // all waves reduce the 8 wave-winners redundantly (no 2nd barrier)
    unsigned long long kk = skeys[buf][lane & 7];
    klo = (unsigned)kk;
    khi = (unsigned)(kk >> 32);
    DPP_MAX64(0x111)
    DPP_MAX64(0x112)
    DPP_MAX64(0x114)
    unsigned flo = (unsigned)__builtin_amdgcn_readlane((int)klo, 7);
    int far = 4095 - (int)(flo & 0xfffu);
    if (t == 0) { fps_idx[b * NSAMP + it] = far; fpsb[it] = far; }
    c = pts[far];
  }
  __syncthreads();
  // fused gather_xyz epilogue: out0 (B,3,S) + nx4 (x,y,z,|.|^2) from LDS
#pragma unroll
  for (int k = 0; k < 2; ++k) {
    int s = k * 512 + t;
    int p = fpsb[s];
    float4 q = pts[p];
    out0[(b * 3 + 0) * 1024 + s] = q.x;
    out0[(b * 3 + 1) * 1024 + s] = q.y;
    out0[(b * 3 + 2) * 1024 + s] = q.z;
    nx4[b * 1024 + s] = q;
  }
}

// ---------------------------------------------------------------------------
// K2a: gather centroid features -> out1 (B,64,S) and ws new_feats (B,S,64)
// ---------------------------------------------------------------------------
__global__ __launch_bounds__(256) void gather_feats_kernel(const float* __restrict__ feats,
                                                           const int* __restrict__ fps,
                                                           float* __restrict__ out1,
                                                           float* __restrict__ nf) {
  int i = blockIdx.x * 256 + threadIdx.x;  // 8*64*1024
  int s = i & 1023, c = (i >> 10) & 63, b = i >> 16;
  int p = fps[(b << 10) + s];
  float v = feats[((size_t)(b * 64 + c)) * NPTS + p];
  out1[(b * 64 + c) * 1024 + s] = v;
  nf[(((b << 10) + s) << 6) + c] = v;
}

// ---------------------------------------------------------------------------
// K3: exact ordered top-32 nearest neighbors per (b,s).
// One wave per row; 64 distance keys per lane in VGPRs, key = (mapped_bits<<32)|n
// so ascending-u64 order == ascending (distance, index) order (lax.top_k ties).
// dot uses an FMA-accumulated chain (matches the reference einsum lowering).
// ---------------------------------------------------------------------------
__device__ __forceinline__ unsigned long long mk_key(float xn, float yn, float zn,
                                                     float sq, float cx, float cy,
                                                     float cz, float src2, int n) {
  float dot = __fmaf_rn(zn, cz, __fmaf_rn(yn, cy, __fmul_rn(xn, cx)));
  float d = __fadd_rn(__fadd_rn(__fmul_rn(-2.0f, dot), src2), sq);
  unsigned mb = __float_as_uint(d);
  mb = (mb & 0x80000000u) ? ~mb : (mb | 0x80000000u);
  return ((unsigned long long)mb << 32) | (unsigned)n;
}

__global__ __launch_bounds__(256, 2) void knn_kernel(const float* __restrict__ xyz,
                                                     const float* __restrict__ sqnorm,
                                                     const float4* __restrict__ nx4,
                                                     int* __restrict__ knn) {
  const int lane = threadIdx.x & 63;
  const int w = threadIdx.x >> 6;
  const int row = blockIdx.x * 4 + w;  // 0..8191
  const int b = row >> 10;
  const float4 c4 = nx4[row];
  const float cx = c4.x, cy = c4.y, cz = c4.z, src2 = c4.w;
  const float4* x4 = (const float4*)(xyz + (size_t)b * 3 * NPTS);
  const float4* y4 = (const float4*)(xyz + (size_t)b * 3 * NPTS + NPTS);
  const float4* z4 = (const float4*)(xyz + (size_t)b * 3 * NPTS + 2 * NPTS);
  const float4* s4 = (const float4*)(sqnorm + (size_t)b * NPTS);
  unsigned long long key[64];
#pragma unroll
  for (int jj = 0; jj < 16; ++jj) {
    int vi = jj * 64 + lane;
    float4 xv = x4[vi], yv = y4[vi], zv = z4[vi], sv = s4[vi];
    int n0 = vi * 4;
    key[jj * 4 + 0] = mk_key(xv.x, yv.x, zv.x, sv.x, cx, cy, cz, src2, n0);
    key[jj * 4 + 1] = mk_key(xv.y, yv.y, zv.y, sv.y, cx, cy, cz, src2, n0 + 1);
    key[jj * 4 + 2] = mk_key(xv.z, yv.z, zv.z, sv.z, cx, cy, cz, src2, n0 + 2);
    key[jj * 4 + 3] = mk_key(xv.w, yv.w, zv.w, sv.w, cx, cy, cz, src2, n0 + 3);
  }
  unsigned long long last = 0ull;
  const int out_base = row * KNN_K;
#pragma unroll 1
  for (int r = 0; r < KNN_K; ++r) {
    unsigned long long cur = ~0ull;
#pragma unroll
    for (int j = 0; j < 64; ++j) {
      unsigned long long k = key[j];
      if (k > last && k < cur) cur = k;
    }
#pragma unroll
    for (int off = 32; off > 0; off >>= 1) {
      unsigned long long o = __shfl_xor(cur, off);
      cur = (o < cur) ? o : cur;
    }
    last = cur;
    if (lane == r) knn[out_base + r] = (int)(unsigned)(cur & 0xffffffffull);
  }
}

// ---------------------------------------------------------------------------
// K4: per-batch sum / sumsq of diff (f64) for std(ddof=1)
// ---------------------------------------------------------------------------
__global__ __launch_bounds__(256) void stats_kernel(const float* __restrict__ feats,
                                                    const float* __restrict__ nf,
                                                    const int* __restrict__ knn,
                                                    double* __restrict__ stats) {
  const int b = blockIdx.x >> 5;
  const int chunk = blockIdx.x & 31;
  const int base = chunk * 65536;
  double sm = 0.0, sq = 0.0;
  for (int i = 0; i < 256; ++i) {
    int e = base + i * 256 + threadIdx.x;   // e < 2097152 per batch
    int c = e >> 15;                        // 0..63
    int sk = e & 32767;
    int s = sk >> 5, j = sk & 31;
    int p = knn[((((b << 10) + s)) << 5) + j];
    float f = feats[((size_t)(b * 64 + c)) * NPTS + p];
    float m = nf[(((b << 10) + s) << 6) + c];
    double d = (double)__fsub_rn(f, m);
    sm += d;
    sq += d * d;
  }
#pragma unroll
  for (int off = 32; off > 0; off >>= 1) {
    sm += __shfl_down(sm, off);
    sq += __shfl_down(sq, off);
  }
  __shared__ double red[8];
  int w = threadIdx.x >> 6;
  if ((threadIdx.x & 63) == 0) { red[w * 2] = sm; red[w * 2 + 1] = sq; }
  __syncthreads();
  if (threadIdx.x == 0) {
    atomicAdd(&stats[b * 2 + 0], red[0] + red[2] + red[4] + red[6]);
    atomicAdd(&stats[b * 2 + 1], red[1] + red[3] + red[5] + red[7]);
  }
}

// ---------------------------------------------------------------------------
// K5: final normalized/affine output, (B,128,S,k) coalesced along (s,k)
// ---------------------------------------------------------------------------
__global__ __launch_bounds__(256) void out_kernel(const float* __restrict__ feats,
                                                  const float* __restrict__ nf,
                                                  const int* __restrict__ knn,
                                                  const double* __restrict__ stats,
                                                  const float* __restrict__ alpha,
                                                  const float* __restrict__ beta,
                                                  float* __restrict__ out2) {
  const int plane = blockIdx.x;  // b*64 + c
  const int b = plane >> 6, c = plane & 63;
  const int sk = blockIdx.y * 256 + threadIdx.x;  // 0..32767
  const int s = sk >> 5, j = sk & 31;
  const double n = 2097152.0;
  double sm = stats[b * 2], sqs = stats[b * 2 + 1];
  double var = (sqs - sm * sm / n) / (n - 1.0);
  float stdf = (float)sqrt(var);
  float denom = stdf + EPSF;
  int p = knn[((((b << 10) + s)) << 5) + j];
  float f = feats[((size_t)(b * 64 + c)) * NPTS + p];
  float m = nf[(((b << 10) + s) << 6) + c];
  float diff = __fsub_rn(f, m);
  float g = alpha[c] * (diff / denom) + beta[c];
  size_t o1 = (((size_t)(b * 128 + c) << 10) + (size_t)s) * 32 + j;
  size_t o2 = (((size_t)(b * 128 + 64 + c) << 10) + (size_t)s) * 32 + j;
  out2[o1] = g;
  out2[o2] = g - m;
}

extern "C" void kernel_launch(void* const* d_in, const int* in_sizes, int n_in,
                              void* d_out, int out_size, void* d_ws, size_t ws_size,
                              hipStream_t stream) {
  (void)in_sizes; (void)n_in; (void)out_size; (void)ws_size;
  const float* xyz   = (const float*)d_in[0];  // (8,3,4096)
  const float* feats = (const float*)d_in[1];  // (8,64,4096)
  const float* alpha = (const float*)d_in[2];  // (64)
  const float* beta  = (const float*)d_in[3];  // (64)
  float* out  = (float*)d_out;
  float* out0 = out;                  // (8,3,1024)    = 24576
  float* out1 = out + 24576;          // (8,64,1024)   = 524288
  float* out2 = out + 24576 + 524288; // (8,128,1024,32)

  char* ws = (char*)d_ws;
  int*    fps   = (int*)ws;                   // 32768 B
  float*  sqn   = (float*)(ws + 32768);       // 131072 B
  float4* nx4   = (float4*)(ws + 163840);     // 131072 B (16B aligned)
  float*  nf    = (float*)(ws + 294912);      // 2097152 B
  int*    knn   = (int*)(ws + 2392064);       // 1048576 B
  double* stats = (double*)(ws + 3440640);    // 128 B

  hipMemsetAsync(stats, 0, 128, stream);
  fps_kernel<<<8, 512, 0, stream>>>(xyz, fps, sqn, out0, nx4);
  gather_feats_kernel<<<2048, 256, 0, stream>>>(feats, fps, out1, nf);
  knn_kernel<<<2048, 256, 0, stream>>>(xyz, sqn, nx4, knn);
  stats_kernel<<<256, 256, 0, stream>>>(feats, nf, knn, stats);
  out_kernel<<<dim3(512, 128), 256, 0, stream>>>(feats, nf, knn, stats, alpha, beta, out2);
}

// Round 11
// 958.752 us; speedup vs baseline: 1.3011x; 1.0191x over previous
//
#include <hip/hip_runtime.h>

#define NPTS 4096
#define NSAMP 1024
#define KNN_K 32
#define FDIM 64
#define EPSF 1e-5f

typedef float v2f __attribute__((ext_vector_type(2)));

// ---------------------------------------------------------------------------
// K1: farthest point sampling -- R3/R10 structure (empirical best): one block
// per batch, 512 threads (8 waves, 2/SIMD). 8 pts/lane (pk-f32 pairs, contract
// off, bit-exact). Serial ascending cmp/select per-lane argmax, packed 44-bit
// key (dist<<12)|(4095-idx), 6x DPP_MAX64 -> lane63 -> LDS, ONE barrier,
// redundant 3x DPP_MAX64 stage-2, readlane -> far, pts[far] broadcast.
// Fused epilogue emits out0 + nx4 from LDS.
// ---------------------------------------------------------------------------
#define DPP_MAX64(CTRL)                                                          \
  {                                                                              \
    unsigned _olo = (unsigned)__builtin_amdgcn_update_dpp(0, (int)klo, CTRL,     \
                                                          0xf, 0xf, true);       \
    unsigned _ohi = (unsigned)__builtin_amdgcn_update_dpp(0, (int)khi, CTRL,     \
                                                          0xf, 0xf, true);       \
    unsigned long long _ok = ((unsigned long long)_ohi << 32) | _olo;            \
    unsigned long long _ck = ((unsigned long long)khi << 32) | klo;              \
    if (_ok > _ck) { klo = _olo; khi = _ohi; }                                   \
  }

__global__ __launch_bounds__(512) void fps_kernel(const float* __restrict__ xyz,
                                                  int* __restrict__ fps_idx,
                                                  float* __restrict__ sqnorm,
                                                  float* __restrict__ out0,
                                                  float4* __restrict__ nx4) {
#pragma clang fp contract(off)
  __shared__ float4 pts[NPTS];
  __shared__ unsigned long long skeys[2][8];
  __shared__ int fpsb[NSAMP];
  const int b = blockIdx.x, t = threadIdx.x;
  const int lane = t & 63, w = t >> 6;
  const float* xb = xyz + (size_t)b * 3 * NPTS;
  v2f px[4], py[4], pz[4], dst[4];
#pragma unroll
  for (int j = 0; j < 4; ++j) {
    int p0 = (2 * j) * 512 + t, p1 = (2 * j + 1) * 512 + t;
    float x0 = xb[p0], y0 = xb[NPTS + p0], z0 = xb[2 * NPTS + p0];
    float x1 = xb[p1], y1 = xb[NPTS + p1], z1 = xb[2 * NPTS + p1];
    float sq0 = __fadd_rn(__fadd_rn(__fmul_rn(x0, x0), __fmul_rn(y0, y0)),
                          __fmul_rn(z0, z0));
    float sq1 = __fadd_rn(__fadd_rn(__fmul_rn(x1, x1), __fmul_rn(y1, y1)),
                          __fmul_rn(z1, z1));
    pts[p0] = make_float4(x0, y0, z0, sq0);
    pts[p1] = make_float4(x1, y1, z1, sq1);
    sqnorm[b * NPTS + p0] = sq0;
    sqnorm[b * NPTS + p1] = sq1;
    px[j].x = x0; px[j].y = x1;
    py[j].x = y0; py[j].y = y1;
    pz[j].x = z0; pz[j].y = z1;
    dst[j].x = 1e10f;
    dst[j].y = 1e10f;
  }
  if (t == 0) { fps_idx[b * NSAMP] = 0; fpsb[0] = 0; }
  __syncthreads();
  float4 c = pts[0];
  for (int it = 1; it < NSAMP; ++it) {
    v2f vcx, vcy, vcz;
    vcx.x = c.x; vcx.y = c.x;
    vcy.x = c.y; vcy.y = c.y;
    vcz.x = c.z; vcz.y = c.z;
#pragma unroll
    for (int j = 0; j < 4; ++j) {
      v2f dx = px[j] - vcx;
      v2f dy = py[j] - vcy;
      v2f dz = pz[j] - vcz;
      v2f dd = (dx * dx + dy * dy) + dz * dz;
      dst[j].x = fminf(dst[j].x, dd.x);
      dst[j].y = fminf(dst[j].y, dd.y);
    }
    float bv = -1.0f;
    int bi = 0;
#pragma unroll
    for (int k = 0; k < 8; ++k) {
      float nd = (k & 1) ? dst[k >> 1].y : dst[k >> 1].x;
      int n = k * 512 + t;
      if (nd > bv) { bv = nd; bi = n; }  // k ascending -> lowest idx on tie
    }
    unsigned bvb = __float_as_uint(bv);
    unsigned klo = (bvb << 12) | (unsigned)(4095 - bi);
    unsigned khi = bvb >> 20;
    DPP_MAX64(0x111)
    DPP_MAX64(0x112)
    DPP_MAX64(0x114)
    DPP_MAX64(0x118)
    DPP_MAX64(0x142)
    DPP_MAX64(0x143)
    const int buf = it & 1;
    if (lane == 63) skeys[buf][w] = ((unsigned long long)khi << 32) | klo;
    __syncthreads();
    unsigned long long kk = skeys[buf][lane & 7];
    klo = (unsigned)kk;
    khi = (unsigned)(kk >> 32);
    DPP_MAX64(0x111)
    DPP_MAX64(0x112)
    DPP_MAX64(0x114)
    unsigned flo = (unsigned)__builtin_amdgcn_readlane((int)klo, 7);
    int far = 4095 - (int)(flo & 0xfffu);
    if (t == 0) { fps_idx[b * NSAMP + it] = far; fpsb[it] = far; }
    c = pts[far];
  }
  __syncthreads();
#pragma unroll
  for (int k = 0; k < 2; ++k) {
    int s = k * 512 + t;
    int p = fpsb[s];
    float4 q = pts[p];
    out0[(b * 3 + 0) * 1024 + s] = q.x;
    out0[(b * 3 + 1) * 1024 + s] = q.y;
    out0[(b * 3 + 2) * 1024 + s] = q.z;
    nx4[b * 1024 + s] = q;
  }
}

// ---------------------------------------------------------------------------
// K2 (merged): blocks 0..2047 = exact ordered top-32 kNN (one wave per row,
// unchanged validated body); blocks 2048..2559 = gather_feats vectorized x4
// (int4 fps load, float4 out1 store, nf scatter). Both depend only on fps
// outputs -> one dispatch, one fewer launch gap.
// ---------------------------------------------------------------------------
__device__ __forceinline__ unsigned long long mk_key(float xn, float yn, float zn,
                                                     float sq, float cx, float cy,
                                                     float cz, float src2, int n) {
  float dot = __fmaf_rn(zn, cz, __fmaf_rn(yn, cy, __fmul_rn(xn, cx)));
  float d = __fadd_rn(__fadd_rn(__fmul_rn(-2.0f, dot), src2), sq);
  unsigned mb = __float_as_uint(d);
  mb = (mb & 0x80000000u) ? ~mb : (mb | 0x80000000u);
  return ((unsigned long long)mb << 32) | (unsigned)n;
}

__global__ __launch_bounds__(256) void mid_kernel(const float* __restrict__ xyz,
                                                  const float* __restrict__ sqnorm,
                                                  const float4* __restrict__ nx4,
                                                  int* __restrict__ knn,
                                                  const float* __restrict__ feats,
                                                  const int* __restrict__ fps,
                                                  float* __restrict__ out1,
                                                  float* __restrict__ nf) {
  if (blockIdx.x < 2048) {
    const int lane = threadIdx.x & 63;
    const int w = threadIdx.x >> 6;
    const int row = blockIdx.x * 4 + w;  // 0..8191
    const int b = row >> 10;
    const float4 c4 = nx4[row];
    const float cx = c4.x, cy = c4.y, cz = c4.z, src2 = c4.w;
    const float4* x4 = (const float4*)(xyz + (size_t)b * 3 * NPTS);
    const float4* y4 = (const float4*)(xyz + (size_t)b * 3 * NPTS + NPTS);
    const float4* z4 = (const float4*)(xyz + (size_t)b * 3 * NPTS + 2 * NPTS);
    const float4* s4 = (const float4*)(sqnorm + (size_t)b * NPTS);
    unsigned long long key[64];
#pragma unroll
    for (int jj = 0; jj < 16; ++jj) {
      int vi = jj * 64 + lane;
      float4 xv = x4[vi], yv = y4[vi], zv = z4[vi], sv = s4[vi];
      int n0 = vi * 4;
      key[jj * 4 + 0] = mk_key(xv.x, yv.x, zv.x, sv.x, cx, cy, cz, src2, n0);
      key[jj * 4 + 1] = mk_key(xv.y, yv.y, zv.y, sv.y, cx, cy, cz, src2, n0 + 1);
      key[jj * 4 + 2] = mk_key(xv.z, yv.z, zv.z, sv.z, cx, cy, cz, src2, n0 + 2);
      key[jj * 4 + 3] = mk_key(xv.w, yv.w, zv.w, sv.w, cx, cy, cz, src2, n0 + 3);
    }
    unsigned long long last = 0ull;
    const int out_base = row * KNN_K;
#pragma unroll 1
    for (int r = 0; r < KNN_K; ++r) {
      unsigned long long cur = ~0ull;
#pragma unroll
      for (int j = 0; j < 64; ++j) {
        unsigned long long k = key[j];
        if (k > last && k < cur) cur = k;
      }
#pragma unroll
      for (int off = 32; off > 0; off >>= 1) {
        unsigned long long o = __shfl_xor(cur, off);
        cur = (o < cur) ? o : cur;
      }
      last = cur;
      if (lane == r) knn[out_base + r] = (int)(unsigned)(cur & 0xffffffffull);
    }
  } else {
    int i = (blockIdx.x - 2048) * 256 + threadIdx.x;  // 0..131071
    int s4i = i & 255, c = (i >> 8) & 63, b = i >> 14;
    int s0 = s4i * 4;
    const int4 p = *(const int4*)&fps[(b << 10) + s0];
    const float* fc = feats + (size_t)(b * 64 + c) * NPTS;
    float v0 = fc[p.x], v1 = fc[p.y], v2 = fc[p.z], v3 = fc[p.w];
    *(float4*)&out1[(b * 64 + c) * 1024 + s0] = make_float4(v0, v1, v2, v3);
    nf[(((b << 10) + s0 + 0) << 6) + c] = v0;
    nf[(((b << 10) + s0 + 1) << 6) + c] = v1;
    nf[(((b << 10) + s0 + 2) << 6) + c] = v2;
    nf[(((b << 10) + s0 + 3) << 6) + c] = v3;
  }
}

// ---------------------------------------------------------------------------
// K4: per-batch sum / sumsq of diff, x4 vectorized (int4 knn, 4 gathers),
// f32 inner accumulators (error ~1e-5 rel on std, threshold 0.2), f64 reduce.
// ---------------------------------------------------------------------------
__global__ __launch_bounds__(256) void stats_kernel(const float* __restrict__ feats,
                                                    const float* __restrict__ nf,
                                                    const int* __restrict__ knn,
                                                    double* __restrict__ stats) {
  const int b = blockIdx.x >> 5;
  const int chunk = blockIdx.x & 31;
  const float* fb = feats + (size_t)b * 64 * NPTS;
  float sm = 0.0f, sq = 0.0f;
  for (int it = 0; it < 64; ++it) {
    int e0 = chunk * 65536 + (it * 256 + threadIdx.x) * 4;  // j0 4-aligned
    int c = e0 >> 15;
    int sk = e0 & 32767;
    int s = sk >> 5, j0 = sk & 31;
    const int4 pq = *(const int4*)&knn[(((b << 10) + s) << 5) + j0];
    float m = nf[(((b << 10) + s) << 6) + c];
    const float* fc = fb + (size_t)c * NPTS;
    float d0 = __fsub_rn(fc[pq.x], m);
    float d1 = __fsub_rn(fc[pq.y], m);
    float d2 = __fsub_rn(fc[pq.z], m);
    float d3 = __fsub_rn(fc[pq.w], m);
    sm += (d0 + d1) + (d2 + d3);
    sq = fmaf(d0, d0, fmaf(d1, d1, fmaf(d2, d2, fmaf(d3, d3, sq))));
  }
  double dsm = (double)sm, dsq = (double)sq;
#pragma unroll
  for (int off = 32; off > 0; off >>= 1) {
    dsm += __shfl_down(dsm, off);
    dsq += __shfl_down(dsq, off);
  }
  __shared__ double red[8];
  int w = threadIdx.x >> 6;
  if ((threadIdx.x & 63) == 0) { red[w * 2] = dsm; red[w * 2 + 1] = dsq; }
  __syncthreads();
  if (threadIdx.x == 0) {
    atomicAdd(&stats[b * 2 + 0], red[0] + red[2] + red[4] + red[6]);
    atomicAdd(&stats[b * 2 + 1], red[1] + red[3] + red[5] + red[7]);
  }
}

// ---------------------------------------------------------------------------
// K5: final output, x4 vectorized: int4 knn, 4 gathers, float4 stores to both
// halves (j0 4-aligned -> 16B aligned). grid (512 planes, 32), 256 thr.
// ---------------------------------------------------------------------------
__global__ __launch_bounds__(256) void out_kernel(const float* __restrict__ feats,
                                                  const float* __restrict__ nf,
                                                  const int* __restrict__ knn,
                                                  const double* __restrict__ stats,
                                                  const float* __restrict__ alpha,
                                                  const float* __restrict__ beta,
                                                  float* __restrict__ out2) {
  const int plane = blockIdx.x;  // b*64 + c
  const int b = plane >> 6, c = plane & 63;
  const double n = 2097152.0;
  double sm = stats[b * 2], sqs = stats[b * 2 + 1];
  double var = (sqs - sm * sm / n) / (n - 1.0);
  float denom = (float)sqrt(var) + EPSF;
  float inv = 1.0f / denom;
  float al = alpha[c], be = beta[c];
  int sk0 = (blockIdx.y * 256 + threadIdx.x) * 4;  // 0..32764, j0 4-aligned
  int s = sk0 >> 5, j0 = sk0 & 31;
  const int4 pq = *(const int4*)&knn[(((b << 10) + s) << 5) + j0];
  const float* fc = feats + (size_t)(b * 64 + c) * NPTS;
  float m = nf[(((b << 10) + s) << 6) + c];
  float g0 = al * (__fsub_rn(fc[pq.x], m) * inv) + be;
  float g1 = al * (__fsub_rn(fc[pq.y], m) * inv) + be;
  float g2 = al * (__fsub_rn(fc[pq.z], m) * inv) + be;
  float g3 = al * (__fsub_rn(fc[pq.w], m) * inv) + be;
  size_t o1 = (((size_t)(b * 128 + c) << 10) + (size_t)s) * 32 + j0;
  size_t o2 = (((size_t)(b * 128 + 64 + c) << 10) + (size_t)s) * 32 + j0;
  *(float4*)&out2[o1] = make_float4(g0, g1, g2, g3);
  *(float4*)&out2[o2] = make_float4(g0 - m, g1 - m, g2 - m, g3 - m);
}

extern "C" void kernel_launch(void* const* d_in, const int* in_sizes, int n_in,
                              void* d_out, int out_size, void* d_ws, size_t ws_size,
                              hipStream_t stream) {
  (void)in_sizes; (void)n_in; (void)out_size; (void)ws_size;
  const float* xyz   = (const float*)d_in[0];  // (8,3,4096)
  const float* feats = (const float*)d_in[1];  // (8,64,4096)
  const float* alpha = (const float*)d_in[2];  // (64)
  const float* beta  = (const float*)d_in[3];  // (64)
  float* out  = (float*)d_out;
  float* out0 = out;                  // (8,3,1024)    = 24576
  float* out1 = out + 24576;          // (8,64,1024)   = 524288
  float* out2 = out + 24576 + 524288; // (8,128,1024,32)

  char* ws = (char*)d_ws;
  int*    fps   = (int*)ws;                   // 32768 B
  float*  sqn   = (float*)(ws + 32768);       // 131072 B
  float4* nx4   = (float4*)(ws + 163840);     // 131072 B (16B aligned)
  float*  nf    = (float*)(ws + 294912);      // 2097152 B
  int*    knn   = (int*)(ws + 2392064);       // 1048576 B
  double* stats = (double*)(ws + 3440640);    // 128 B

  hipMemsetAsync(stats, 0, 128, stream);
  fps_kernel<<<8, 512, 0, stream>>>(xyz, fps, sqn, out0, nx4);
  mid_kernel<<<2560, 256, 0, stream>>>(xyz, sqn, nx4, knn, feats, fps, out1, nf);
  stats_kernel<<<256, 256, 0, stream>>>(feats, nf, knn, stats);
  out_kernel<<<dim3(512, 32), 256, 0, stream>>>(feats, nf, knn, stats, alpha, beta, out2);
}